// Round 7
// baseline (344.962 us; speedup 1.0000x reference)
//
#include <hip/hip_runtime.h>

typedef __bf16 bf16;
typedef __bf16 bf16x4 __attribute__((ext_vector_type(4)));
typedef __bf16 bf16x8 __attribute__((ext_vector_type(8)));
typedef float  f32x4  __attribute__((ext_vector_type(4)));

// ---------------------------------------------------------------- helpers
__device__ __forceinline__ void gld16(const void* g, void* l) {
  __builtin_amdgcn_global_load_lds(
      (const __attribute__((address_space(1))) void*)g,
      (__attribute__((address_space(3))) void*)l, 16, 0, 0);
}

// ---------------------------------------------------------------- fused fp32 -> bf16 (all three tensors, one launch)
__global__ void f2bf_all(const float* __restrict__ x, bf16* __restrict__ xo,
                         const float* __restrict__ w1, bf16* __restrict__ w1o,
                         const float* __restrict__ w2, bf16* __restrict__ w2o) {
  int i = blockIdx.x * blockDim.x + threadIdx.x;   // grid covers 2097152 float4s
  const float* in; bf16* out; int idx;
  if (i < 1048576)      { in = x;  out = xo;  idx = i; }
  else if (i < 1835008) { in = w1; out = w1o; idx = i - 1048576; }
  else                  { in = w2; out = w2o; idx = i - 1835008; }
  float4 v = reinterpret_cast<const float4*>(in)[idx];
  bf16x4 o = { (bf16)v.x, (bf16)v.y, (bf16)v.z, (bf16)v.w };
  reinterpret_cast<bf16x4*>(out)[idx] = o;
}

// ---------------------------------------------------------------- GEMM: C[M,N] = A[M,K] * B[N,K]^T + bias
// MODE 0 (BN=128): QKV epilogue. Q/K scatter to [sec][B*H][S][64] (q scaled
//   by 0.125*log2e); V section writes V^T into the V-third of QKV as
//   [B*H][64][2048] (4 consecutive s at fixed d = one bf16x4 store).
// MODE 1 (BN=64): out-proj epilogue -> fp32 C += bias
template<int MODE, int BN>
__global__ __launch_bounds__(256)
void gemm_bt(const bf16* __restrict__ A, const bf16* __restrict__ B,
             const float* __restrict__ bias, void* __restrict__ Cout,
             int K, int N) {
  __shared__ bf16 As[128 * 64];
  __shared__ bf16 Bs[BN * 64];
  const int tid  = threadIdx.x;
  const int wave = tid >> 6, lane = tid & 63;
  const int quad = lane >> 4, l16 = lane & 15;
  const int bm = blockIdx.x * 128, bn = blockIdx.y * BN;
  constexpr int NI  = (BN == 128) ? 4 : 2;
  constexpr int BCH = BN / 32;
  const int wr = (BN == 128) ? (wave >> 1) * 64 : wave * 32;
  const int wc = (BN == 128) ? (wave & 1) * 64 : 0;
  const int arow = lane >> 3;
  const int acol = (lane & 7) * 8;

  f32x4 acc[NI][4] = {};

  const bf16* Ab = A + (size_t)bm * K;
  const bf16* Bb = B + (size_t)bn * K;

  for (int k0 = 0; k0 < K; k0 += 64) {
#pragma unroll
    for (int i = 0; i < 4; ++i) {
      int c = wave * 4 + i;
      gld16(Ab + (size_t)(c * 8 + arow) * K + k0 + acol, As + c * 512);
    }
#pragma unroll
    for (int i = 0; i < BCH; ++i) {
      int c = wave * BCH + i;
      gld16(Bb + (size_t)(c * 8 + arow) * K + k0 + acol, Bs + c * 512);
    }
    __syncthreads();
#pragma unroll
    for (int kk = 0; kk < 64; kk += 32) {
      bf16x8 af[NI], bfr[4];
#pragma unroll
      for (int i = 0; i < NI; ++i)
        af[i]  = *(const bf16x8*)(As + (wr + i * 16 + l16) * 64 + kk + quad * 8);
#pragma unroll
      for (int j = 0; j < 4; ++j)
        bfr[j] = *(const bf16x8*)(Bs + (wc + j * 16 + l16) * 64 + kk + quad * 8);
#pragma unroll
      for (int i = 0; i < NI; ++i)
#pragma unroll
        for (int j = 0; j < 4; ++j)
          acc[i][j] = __builtin_amdgcn_mfma_f32_16x16x32_bf16(af[i], bfr[j], acc[i][j], 0, 0, 0);
    }
    __syncthreads();
  }

  if constexpr (MODE == 0) {
    bf16* Q = (bf16*)Cout;  // [3][32][2048][64]; V-third holds V^T [32][64][2048]
#pragma unroll
    for (int j = 0; j < 4; ++j) {
      int col = bn + wc + j * 16 + l16;
      float bv  = bias[col];
      int sec = col >> 10, rem = col & 1023;
      int h = rem >> 6, d = rem & 63;
      if (sec < 2) {
        float scl = (sec == 0) ? 0.125f * 1.44269504f : 1.0f;
#pragma unroll
        for (int i = 0; i < NI; ++i) {
#pragma unroll
          for (int r = 0; r < 4; ++r) {
            int row = bm + wr + i * 16 + quad * 4 + r;
            int b = row >> 11, si = row & 2047;
            float v = (acc[i][j][r] + bv) * scl;
            Q[(((size_t)sec * 32 + b * 16 + h) * 2048 + si) * 64 + d] = (bf16)v;
          }
        }
      } else {
#pragma unroll
        for (int i = 0; i < NI; ++i) {
          int row0 = bm + wr + i * 16 + quad * 4;
          int b = row0 >> 11, si = row0 & 2047;
          bf16x4 pk = { (bf16)(acc[i][j][0] + bv), (bf16)(acc[i][j][1] + bv),
                        (bf16)(acc[i][j][2] + bv), (bf16)(acc[i][j][3] + bv) };
          *(bf16x4*)(Q + (size_t)2 * 4194304 +
                     ((size_t)(b * 16 + h) * 64 + d) * 2048 + si) = pk;
        }
      }
    }
  } else {
    float* C = (float*)Cout;
#pragma unroll
    for (int j = 0; j < 4; ++j) {
      int col = bn + wc + j * 16 + l16;
      float bv = bias[col];
#pragma unroll
      for (int i = 0; i < NI; ++i)
#pragma unroll
        for (int r = 0; r < 4; ++r) {
          int row = bm + wr + i * 16 + quad * 4 + r;
          C[(size_t)row * N + col] = acc[i][j][r] + bv;
        }
    }
  }
}

// ---------------------------------------------------------------- flash attention v14 = barrier-free (phase-lock removal)
// History: v8 78.5 / v11 76.8 / v12 79.7 / v13 77.9 us — occupancy rose
// 18->25% with ZERO duration change. Pipe budget per CU: MFMA 16.6us,
// DS 21us, exp2(trans, 1/4-rate) 27us, misc ~10us. max=27 but SUM=75 ~=
// measured 78 -> pipes never overlap: barriers every ~1200cy re-align all
// waves in a block to the same phase (QK | exp2 | PV), and co-resident
// blocks settle into lockstep (identical periodic structure, shared pipe
// contention). Extra waves at the SAME phase add nothing -> occupancy
// invariance. v9's 2x-iteration regression fits too (per-iter latency
// overhead doubled).
// v14: remove the phase-locking mechanism. The only shared state was Ks;
// read K fragments DIRECT from global instead (L2-resident via XCD-local
// grid: per-XCD K replay ~2.8 TB/s < 4.3 TB/s per-XCD L2 BW). Loop now has
// ZERO __syncthreads -> waves free-run and drift, overlapping MFMA/trans/
// LDS/VMEM pipes across 8-12 resident waves. Also cuts 16 ds_read_b128 +
// 4 gld16 per wave-tile (LDS 21->11us) and LDS size 34.8->18.4KB.
// Kept: 32-qrow x 128-kcol tile, K-chunked pipeline (s[2][4]+kf[4] live,
// ~148 total regs -> 3 waves/SIMD under (256,3); v13 proved no spill),
// S^T-form QK, per-wave Ps round-trip (in-order DS, no barrier needed),
// V direct from global V^T, split-KV x2 (grid 32x16x2), f32 partial
// epilogue + combine. Q pre-scaled 0.125*log2e -> exp2.
// Tripwire: WRITE_SIZE >> 33MB => (256,3) spilled => revert to (256,2).
__global__ __launch_bounds__(256, 3)
void attn_kernel(const bf16* __restrict__ QKV, const bf16* __restrict__ Vt,
                 float* __restrict__ Opart, float* __restrict__ lpart) {
  __shared__ bf16 Ps[4][32 * 72];

  const int bh = blockIdx.x;               // XCD-locality: bh is the fast dim
  const int q0 = blockIdx.y * 128;
  const int half = blockIdx.z;             // KV split: tiles [half*8, half*8+8)
  const int kt0 = half * 8;
  const bf16* Qg = QKV + ((size_t)bh * 2048 + q0) * 64;
  const bf16* Kg = QKV + (size_t)32 * 2048 * 64 + (size_t)bh * 2048 * 64;
  const bf16* Vg = Vt + (size_t)bh * 64 * 2048;
  float* Oh = Opart + (size_t)half * 4194304 + (size_t)bh * 2048 * 64;
  float* lh = lpart + (size_t)half * 65536 + (size_t)bh * 2048;

  const int tid  = threadIdx.x;
  const int wave = tid >> 6, lane = tid & 63;
  const int quad = lane >> 4, l16 = lane & 15;
  bf16* Pw = &Ps[wave][0];

  // Q fragments in registers (B-operand), reused across the 8 K-tiles
  bf16x8 aq[2][2];
#pragma unroll
  for (int i = 0; i < 2; ++i)
#pragma unroll
    for (int kh = 0; kh < 2; ++kh)
      aq[i][kh] = *(const bf16x8*)(Qg + (size_t)(wave * 32 + i * 16 + l16) * 64 +
                                   kh * 32 + quad * 8);

  float rs[2] = {0.f, 0.f};             // per-lane partial row sums (qrow = i*16+l16)
  f32x4 o[2][4] = {};

  for (int kt = 0; kt < 8; ++kt) {
    const int g = kt0 + kt;             // global K-tile index

#pragma unroll
    for (int c = 0; c < 2; ++c) {
      // V fragments for this chunk (kk = c*2 .. c*2+1) — issue early,
      // latency hides under the K loads + QK MFMAs below
      bf16x8 bv[2][4];
#pragma unroll
      for (int kc = 0; kc < 2; ++kc)
#pragma unroll
        for (int oj = 0; oj < 4; ++oj)
          bv[kc][oj] = *(const bf16x8*)(Vg + (size_t)(oj * 16 + l16) * 2048 +
                                        g * 128 + (c * 2 + kc) * 32 + quad * 8);

      // ---- S^T chunk = K Q^T, K direct from global (L2-hit)
      // lane holds S[qrow=l16][kcol=(c*4+nc)*16+quad*4+r]
      f32x4 s[2][4] = {};
#pragma unroll
      for (int kh = 0; kh < 2; ++kh) {
        bf16x8 kf[4];
#pragma unroll
        for (int nc = 0; nc < 4; ++nc)
          kf[nc] = *(const bf16x8*)(Kg +
                     (size_t)(g * 128 + (c * 4 + nc) * 16 + l16) * 64 +
                     kh * 32 + quad * 8);
#pragma unroll
        for (int nc = 0; nc < 4; ++nc) {
          s[0][nc] = __builtin_amdgcn_mfma_f32_16x16x32_bf16(kf[nc], aq[0][kh], s[0][nc], 0, 0, 0);
          s[1][nc] = __builtin_amdgcn_mfma_f32_16x16x32_bf16(kf[nc], aq[1][kh], s[1][nc], 0, 0, 0);
        }
      }

      // ---- P chunk = exp2(S): one b64 LDS write per (i,nc)
#pragma unroll
      for (int i = 0; i < 2; ++i)
#pragma unroll
        for (int nc = 0; nc < 4; ++nc) {
          float p0 = __builtin_amdgcn_exp2f(s[i][nc][0]);
          float p1 = __builtin_amdgcn_exp2f(s[i][nc][1]);
          float p2 = __builtin_amdgcn_exp2f(s[i][nc][2]);
          float p3 = __builtin_amdgcn_exp2f(s[i][nc][3]);
          rs[i] += (p0 + p1) + (p2 + p3);
          bf16x4 pk = { (bf16)p0, (bf16)p1, (bf16)p2, (bf16)p3 };
          *(bf16x4*)(Pw + (i * 16 + l16) * 72 + nc * 16 + quad * 4) = pk;
        }

      // ---- O += P V chunk (per-wave Ps; in-order DS orders write->read)
#pragma unroll
      for (int kc = 0; kc < 2; ++kc) {
#pragma unroll
        for (int i = 0; i < 2; ++i) {
          bf16x8 ap = *(const bf16x8*)(Pw + (i * 16 + l16) * 72 + kc * 32 + quad * 8);
#pragma unroll
          for (int oj = 0; oj < 4; ++oj)
            o[i][oj] = __builtin_amdgcn_mfma_f32_16x16x32_bf16(ap, bv[kc][oj], o[i][oj], 0, 0, 0);
        }
      }
    }
  }

  // ---- finalize row sums: quads hold partials for row l16
#pragma unroll
  for (int i = 0; i < 2; ++i) {
    rs[i] += __shfl_xor(rs[i], 16);
    rs[i] += __shfl_xor(rs[i], 32);
  }

  // ---- epilogue: write UNNORMALIZED f32 partial O + partial row sums
#pragma unroll
  for (int i = 0; i < 2; ++i) {
    if (quad == 0)
      lh[q0 + wave * 32 + i * 16 + l16] = rs[i];
#pragma unroll
    for (int r = 0; r < 4; ++r) {
      int row = q0 + wave * 32 + i * 16 + quad * 4 + r;
#pragma unroll
      for (int oj = 0; oj < 4; ++oj)
        Oh[(size_t)row * 64 + oj * 16 + l16] = o[i][oj][r];
    }
  }
}

// ---------------------------------------------------------------- combine: At = (O0+O1)/(l0+l1), scatter to [B,S,1024] bf16
__global__ void attn_combine(const float* __restrict__ O0, const float* __restrict__ O1,
                             const float* __restrict__ l0, const float* __restrict__ l1,
                             bf16* __restrict__ At) {
  int i = blockIdx.x * blockDim.x + threadIdx.x;   // 1,048,576 f32x4 groups
  int rid = i >> 4, d4 = i & 15;                   // rid = bh*2048+s
  float inv = 1.0f / (l0[rid] + l1[rid]);
  f32x4 a = reinterpret_cast<const f32x4*>(O0)[i];
  f32x4 b = reinterpret_cast<const f32x4*>(O1)[i];
  int bh = rid >> 11, s = rid & 2047;
  int bb = bh >> 4, h = bh & 15;
  bf16x4 ov = { (bf16)((a[0] + b[0]) * inv), (bf16)((a[1] + b[1]) * inv),
                (bf16)((a[2] + b[2]) * inv), (bf16)((a[3] + b[3]) * inv) };
  *reinterpret_cast<bf16x4*>(At + ((size_t)(bb * 2048 + s)) * 1024 + h * 64 + d4 * 4) = ov;
}

// ---------------------------------------------------------------- launch
extern "C" void kernel_launch(void* const* d_in, const int* in_sizes, int n_in,
                              void* d_out, int out_size, void* d_ws, size_t ws_size,
                              hipStream_t stream) {
  const float* x      = (const float*)d_in[0];   // [2,2048,1024]
  const float* qkv_w  = (const float*)d_in[1];   // [3072,1024]
  const float* qkv_b  = (const float*)d_in[2];   // [3072]
  const float* out_w  = (const float*)d_in[3];   // [1024,1024]
  const float* out_b  = (const float*)d_in[4];   // [1024]
  float* out = (float*)d_out;                    // [2,2048,1024] fp32

  char* ws = (char*)d_ws;
  bf16* Xb    = (bf16*)(ws);                     // 8 MB
  bf16* Wqkv  = (bf16*)(ws + 8388608);           // 6 MB
  bf16* Wout  = (bf16*)(ws + 14680064);          // 2 MB
  bf16* QKV   = (bf16*)(ws + 16777216);          // 24 MB: [Q][K] + V^T third
  bf16* At    = (bf16*)(ws + 41943040);          // 8 MB attn output [B,S,1024]
  float* Opart = (float*)(ws + 50331648);        // 2 x 16 MB f32 partial O
  float* lpart = (float*)(ws + 83886080);        // 2 x 256 KB f32 partial sums
  bf16* VtP   = QKV + (size_t)2 * 32 * 2048 * 64; // V^T [32][64][2048]

  f2bf_all<<<8192, 256, 0, stream>>>(x, Xb, qkv_w, Wqkv, out_w, Wout);

  gemm_bt<0, 128><<<dim3(32, 24), 256, 0, stream>>>(Xb, Wqkv, qkv_b, (void*)QKV, 1024, 3072);

  // grid (bh, q_tile, kv_half): blk%8 = bh%8 -> per-head XCD locality
  attn_kernel<<<dim3(32, 16, 2), 256, 0, stream>>>(QKV, VtP, Opart, lpart);

  attn_combine<<<4096, 256, 0, stream>>>(Opart, Opart + 4194304,
                                         lpart, lpart + 65536, At);

  gemm_bt<1, 64><<<dim3(32, 16), 256, 0, stream>>>(At, Wout, out_b, (void*)out, 1024, 1024);
}

// Round 8
// 282.937 us; speedup vs baseline: 1.2192x; 1.2192x over previous
//
#include <hip/hip_runtime.h>

typedef __bf16 bf16;
typedef __bf16 bf16x4 __attribute__((ext_vector_type(4)));
typedef __bf16 bf16x8 __attribute__((ext_vector_type(8)));
typedef float  f32x4  __attribute__((ext_vector_type(4)));

// ---------------------------------------------------------------- helpers
__device__ __forceinline__ void gld16(const void* g, void* l) {
  __builtin_amdgcn_global_load_lds(
      (const __attribute__((address_space(1))) void*)g,
      (__attribute__((address_space(3))) void*)l, 16, 0, 0);
}

// ---------------------------------------------------------------- fused fp32 -> bf16 (all three tensors, one launch)
__global__ void f2bf_all(const float* __restrict__ x, bf16* __restrict__ xo,
                         const float* __restrict__ w1, bf16* __restrict__ w1o,
                         const float* __restrict__ w2, bf16* __restrict__ w2o) {
  int i = blockIdx.x * blockDim.x + threadIdx.x;   // grid covers 2097152 float4s
  const float* in; bf16* out; int idx;
  if (i < 1048576)      { in = x;  out = xo;  idx = i; }
  else if (i < 1835008) { in = w1; out = w1o; idx = i - 1048576; }
  else                  { in = w2; out = w2o; idx = i - 1835008; }
  float4 v = reinterpret_cast<const float4*>(in)[idx];
  bf16x4 o = { (bf16)v.x, (bf16)v.y, (bf16)v.z, (bf16)v.w };
  reinterpret_cast<bf16x4*>(out)[idx] = o;
}

// ---------------------------------------------------------------- GEMM: C[M,N] = A[M,K] * B[N,K]^T + bias
// MODE 0 (BN=128): QKV epilogue. Q/K scatter to [sec][B*H][S][64] (q scaled
//   by 0.125*log2e); V section writes V^T into the V-third of QKV as
//   [B*H][64][2048] (4 consecutive s at fixed d = one bf16x4 store).
// MODE 1 (BN=64): out-proj epilogue -> fp32 C += bias
template<int MODE, int BN>
__global__ __launch_bounds__(256)
void gemm_bt(const bf16* __restrict__ A, const bf16* __restrict__ B,
             const float* __restrict__ bias, void* __restrict__ Cout,
             int K, int N) {
  __shared__ bf16 As[128 * 64];
  __shared__ bf16 Bs[BN * 64];
  const int tid  = threadIdx.x;
  const int wave = tid >> 6, lane = tid & 63;
  const int quad = lane >> 4, l16 = lane & 15;
  const int bm = blockIdx.x * 128, bn = blockIdx.y * BN;
  constexpr int NI  = (BN == 128) ? 4 : 2;
  constexpr int BCH = BN / 32;
  const int wr = (BN == 128) ? (wave >> 1) * 64 : wave * 32;
  const int wc = (BN == 128) ? (wave & 1) * 64 : 0;
  const int arow = lane >> 3;
  const int acol = (lane & 7) * 8;

  f32x4 acc[NI][4] = {};

  const bf16* Ab = A + (size_t)bm * K;
  const bf16* Bb = B + (size_t)bn * K;

  for (int k0 = 0; k0 < K; k0 += 64) {
#pragma unroll
    for (int i = 0; i < 4; ++i) {
      int c = wave * 4 + i;
      gld16(Ab + (size_t)(c * 8 + arow) * K + k0 + acol, As + c * 512);
    }
#pragma unroll
    for (int i = 0; i < BCH; ++i) {
      int c = wave * BCH + i;
      gld16(Bb + (size_t)(c * 8 + arow) * K + k0 + acol, Bs + c * 512);
    }
    __syncthreads();
#pragma unroll
    for (int kk = 0; kk < 64; kk += 32) {
      bf16x8 af[NI], bfr[4];
#pragma unroll
      for (int i = 0; i < NI; ++i)
        af[i]  = *(const bf16x8*)(As + (wr + i * 16 + l16) * 64 + kk + quad * 8);
#pragma unroll
      for (int j = 0; j < 4; ++j)
        bfr[j] = *(const bf16x8*)(Bs + (wc + j * 16 + l16) * 64 + kk + quad * 8);
#pragma unroll
      for (int i = 0; i < NI; ++i)
#pragma unroll
        for (int j = 0; j < 4; ++j)
          acc[i][j] = __builtin_amdgcn_mfma_f32_16x16x32_bf16(af[i], bfr[j], acc[i][j], 0, 0, 0);
    }
    __syncthreads();
  }

  if constexpr (MODE == 0) {
    bf16* Q = (bf16*)Cout;  // [3][32][2048][64]; V-third holds V^T [32][64][2048]
#pragma unroll
    for (int j = 0; j < 4; ++j) {
      int col = bn + wc + j * 16 + l16;
      float bv  = bias[col];
      int sec = col >> 10, rem = col & 1023;
      int h = rem >> 6, d = rem & 63;
      if (sec < 2) {
        float scl = (sec == 0) ? 0.125f * 1.44269504f : 1.0f;
#pragma unroll
        for (int i = 0; i < NI; ++i) {
#pragma unroll
          for (int r = 0; r < 4; ++r) {
            int row = bm + wr + i * 16 + quad * 4 + r;
            int b = row >> 11, si = row & 2047;
            float v = (acc[i][j][r] + bv) * scl;
            Q[(((size_t)sec * 32 + b * 16 + h) * 2048 + si) * 64 + d] = (bf16)v;
          }
        }
      } else {
#pragma unroll
        for (int i = 0; i < NI; ++i) {
          int row0 = bm + wr + i * 16 + quad * 4;
          int b = row0 >> 11, si = row0 & 2047;
          bf16x4 pk = { (bf16)(acc[i][j][0] + bv), (bf16)(acc[i][j][1] + bv),
                        (bf16)(acc[i][j][2] + bv), (bf16)(acc[i][j][3] + bv) };
          *(bf16x4*)(Q + (size_t)2 * 4194304 +
                     ((size_t)(b * 16 + h) * 64 + d) * 2048 + si) = pk;
        }
      }
    }
  } else {
    float* C = (float*)Cout;
#pragma unroll
    for (int j = 0; j < 4; ++j) {
      int col = bn + wc + j * 16 + l16;
      float bv = bias[col];
#pragma unroll
      for (int i = 0; i < NI; ++i)
#pragma unroll
        for (int r = 0; r < 4; ++r) {
          int row = bm + wr + i * 16 + quad * 4 + r;
          C[(size_t)row * N + col] = acc[i][j][r] + bv;
        }
    }
  }
}

// ---------------------------------------------------------------- flash attention v15 = v14 barrier-free, spill-free
// History: v8 78.5 / v11 76.8 / v12 79.7 / v13 77.9 — occupancy 18->25%
// with ZERO dur change; pipe-SUM (~75us) == measured -> phase-lock theory:
// barriers re-align waves each ~1200cy so MFMA/trans/DS/VMEM pipes never
// overlap. v14 tested barrier-free (K direct from L2) but kept the
// (256,3) VGPR cap=84 while ADDING kf[4] (+16 regs) -> spills (WRITE
// 33->92MB, tripwire fired) -> 189us. Theory never cleanly tested.
// v15: identical barrier-free structure, __launch_bounds__(256,2) ->
// natural alloc ~110-130 VGPR, zero spill. Occupancy comes from actual
// usage (<=128 -> up to 4 w/SIMD; <=170 -> 3). This is the clean A/B:
//   dur ~55-70 + MfmaUtil 25+  -> phase-lock confirmed, keep going
//   dur ~78 + clean WRITE 33MB -> theory dead; plateau = per-wave dep
//                                 latency floor; next lever is ILP depth.
// Structure: ZERO __syncthreads in the loop. 32-qrow x 128-kcol tile,
// K-chunked (s[2][4], bv[2][4], kf[4] live), S^T-form QK with K fragments
// direct from global (XCD-local grid keeps K/V in this XCD's L2), per-wave
// Ps round-trip for P transpose (in-order DS), V direct from global V^T,
// split-KV x2 (grid 32x16x2), unnormalized f32 partial epilogue + combine.
// Q pre-scaled 0.125*log2e -> exp2.
__global__ __launch_bounds__(256, 2)
void attn_kernel(const bf16* __restrict__ QKV, const bf16* __restrict__ Vt,
                 float* __restrict__ Opart, float* __restrict__ lpart) {
  __shared__ bf16 Ps[4][32 * 72];

  const int bh = blockIdx.x;               // XCD-locality: bh is the fast dim
  const int q0 = blockIdx.y * 128;
  const int half = blockIdx.z;             // KV split: tiles [half*8, half*8+8)
  const int kt0 = half * 8;
  const bf16* Qg = QKV + ((size_t)bh * 2048 + q0) * 64;
  const bf16* Kg = QKV + (size_t)32 * 2048 * 64 + (size_t)bh * 2048 * 64;
  const bf16* Vg = Vt + (size_t)bh * 64 * 2048;
  float* Oh = Opart + (size_t)half * 4194304 + (size_t)bh * 2048 * 64;
  float* lh = lpart + (size_t)half * 65536 + (size_t)bh * 2048;

  const int tid  = threadIdx.x;
  const int wave = tid >> 6, lane = tid & 63;
  const int quad = lane >> 4, l16 = lane & 15;
  bf16* Pw = &Ps[wave][0];

  // Q fragments in registers (B-operand), reused across the 8 K-tiles
  bf16x8 aq[2][2];
#pragma unroll
  for (int i = 0; i < 2; ++i)
#pragma unroll
    for (int kh = 0; kh < 2; ++kh)
      aq[i][kh] = *(const bf16x8*)(Qg + (size_t)(wave * 32 + i * 16 + l16) * 64 +
                                   kh * 32 + quad * 8);

  float rs[2] = {0.f, 0.f};             // per-lane partial row sums (qrow = i*16+l16)
  f32x4 o[2][4] = {};

  for (int kt = 0; kt < 8; ++kt) {
    const int g = kt0 + kt;             // global K-tile index

#pragma unroll
    for (int c = 0; c < 2; ++c) {
      // V fragments for this chunk (kk = c*2 .. c*2+1) — issue early,
      // latency hides under the K loads + QK MFMAs below
      bf16x8 bv[2][4];
#pragma unroll
      for (int kc = 0; kc < 2; ++kc)
#pragma unroll
        for (int oj = 0; oj < 4; ++oj)
          bv[kc][oj] = *(const bf16x8*)(Vg + (size_t)(oj * 16 + l16) * 2048 +
                                        g * 128 + (c * 2 + kc) * 32 + quad * 8);

      // ---- S^T chunk = K Q^T, K direct from global (L2-hit)
      // lane holds S[qrow=l16][kcol=(c*4+nc)*16+quad*4+r]
      f32x4 s[2][4] = {};
#pragma unroll
      for (int kh = 0; kh < 2; ++kh) {
        bf16x8 kf[4];
#pragma unroll
        for (int nc = 0; nc < 4; ++nc)
          kf[nc] = *(const bf16x8*)(Kg +
                     (size_t)(g * 128 + (c * 4 + nc) * 16 + l16) * 64 +
                     kh * 32 + quad * 8);
#pragma unroll
        for (int nc = 0; nc < 4; ++nc) {
          s[0][nc] = __builtin_amdgcn_mfma_f32_16x16x32_bf16(kf[nc], aq[0][kh], s[0][nc], 0, 0, 0);
          s[1][nc] = __builtin_amdgcn_mfma_f32_16x16x32_bf16(kf[nc], aq[1][kh], s[1][nc], 0, 0, 0);
        }
      }

      // ---- P chunk = exp2(S): one b64 LDS write per (i,nc)
#pragma unroll
      for (int i = 0; i < 2; ++i)
#pragma unroll
        for (int nc = 0; nc < 4; ++nc) {
          float p0 = __builtin_amdgcn_exp2f(s[i][nc][0]);
          float p1 = __builtin_amdgcn_exp2f(s[i][nc][1]);
          float p2 = __builtin_amdgcn_exp2f(s[i][nc][2]);
          float p3 = __builtin_amdgcn_exp2f(s[i][nc][3]);
          rs[i] += (p0 + p1) + (p2 + p3);
          bf16x4 pk = { (bf16)p0, (bf16)p1, (bf16)p2, (bf16)p3 };
          *(bf16x4*)(Pw + (i * 16 + l16) * 72 + nc * 16 + quad * 4) = pk;
        }

      // ---- O += P V chunk (per-wave Ps; in-order DS orders write->read)
#pragma unroll
      for (int kc = 0; kc < 2; ++kc) {
#pragma unroll
        for (int i = 0; i < 2; ++i) {
          bf16x8 ap = *(const bf16x8*)(Pw + (i * 16 + l16) * 72 + kc * 32 + quad * 8);
#pragma unroll
          for (int oj = 0; oj < 4; ++oj)
            o[i][oj] = __builtin_amdgcn_mfma_f32_16x16x32_bf16(ap, bv[kc][oj], o[i][oj], 0, 0, 0);
        }
      }
    }
  }

  // ---- finalize row sums: quads hold partials for row l16
#pragma unroll
  for (int i = 0; i < 2; ++i) {
    rs[i] += __shfl_xor(rs[i], 16);
    rs[i] += __shfl_xor(rs[i], 32);
  }

  // ---- epilogue: write UNNORMALIZED f32 partial O + partial row sums
#pragma unroll
  for (int i = 0; i < 2; ++i) {
    if (quad == 0)
      lh[q0 + wave * 32 + i * 16 + l16] = rs[i];
#pragma unroll
    for (int r = 0; r < 4; ++r) {
      int row = q0 + wave * 32 + i * 16 + quad * 4 + r;
#pragma unroll
      for (int oj = 0; oj < 4; ++oj)
        Oh[(size_t)row * 64 + oj * 16 + l16] = o[i][oj][r];
    }
  }
}

// ---------------------------------------------------------------- combine: At = (O0+O1)/(l0+l1), scatter to [B,S,1024] bf16
__global__ void attn_combine(const float* __restrict__ O0, const float* __restrict__ O1,
                             const float* __restrict__ l0, const float* __restrict__ l1,
                             bf16* __restrict__ At) {
  int i = blockIdx.x * blockDim.x + threadIdx.x;   // 1,048,576 f32x4 groups
  int rid = i >> 4, d4 = i & 15;                   // rid = bh*2048+s
  float inv = 1.0f / (l0[rid] + l1[rid]);
  f32x4 a = reinterpret_cast<const f32x4*>(O0)[i];
  f32x4 b = reinterpret_cast<const f32x4*>(O1)[i];
  int bh = rid >> 11, s = rid & 2047;
  int bb = bh >> 4, h = bh & 15;
  bf16x4 ov = { (bf16)((a[0] + b[0]) * inv), (bf16)((a[1] + b[1]) * inv),
                (bf16)((a[2] + b[2]) * inv), (bf16)((a[3] + b[3]) * inv) };
  *reinterpret_cast<bf16x4*>(At + ((size_t)(bb * 2048 + s)) * 1024 + h * 64 + d4 * 4) = ov;
}

// ---------------------------------------------------------------- launch
extern "C" void kernel_launch(void* const* d_in, const int* in_sizes, int n_in,
                              void* d_out, int out_size, void* d_ws, size_t ws_size,
                              hipStream_t stream) {
  const float* x      = (const float*)d_in[0];   // [2,2048,1024]
  const float* qkv_w  = (const float*)d_in[1];   // [3072,1024]
  const float* qkv_b  = (const float*)d_in[2];   // [3072]
  const float* out_w  = (const float*)d_in[3];   // [1024,1024]
  const float* out_b  = (const float*)d_in[4];   // [1024]
  float* out = (float*)d_out;                    // [2,2048,1024] fp32

  char* ws = (char*)d_ws;
  bf16* Xb    = (bf16*)(ws);                     // 8 MB
  bf16* Wqkv  = (bf16*)(ws + 8388608);           // 6 MB
  bf16* Wout  = (bf16*)(ws + 14680064);          // 2 MB
  bf16* QKV   = (bf16*)(ws + 16777216);          // 24 MB: [Q][K] + V^T third
  bf16* At    = (bf16*)(ws + 41943040);          // 8 MB attn output [B,S,1024]
  float* Opart = (float*)(ws + 50331648);        // 2 x 16 MB f32 partial O
  float* lpart = (float*)(ws + 83886080);        // 2 x 256 KB f32 partial sums
  bf16* VtP   = QKV + (size_t)2 * 32 * 2048 * 64; // V^T [32][64][2048]

  f2bf_all<<<8192, 256, 0, stream>>>(x, Xb, qkv_w, Wqkv, out_w, Wout);

  gemm_bt<0, 128><<<dim3(32, 24), 256, 0, stream>>>(Xb, Wqkv, qkv_b, (void*)QKV, 1024, 3072);

  // grid (bh, q_tile, kv_half): blk%8 = bh%8 -> per-head XCD locality
  attn_kernel<<<dim3(32, 16, 2), 256, 0, stream>>>(QKV, VtP, Opart, lpart);

  attn_combine<<<4096, 256, 0, stream>>>(Opart, Opart + 4194304,
                                         lpart, lpart + 65536, At);

  gemm_bt<1, 64><<<dim3(32, 16), 256, 0, stream>>>(At, Wout, out_b, (void*)out, 1024, 1024);
}

// Round 9
// 228.137 us; speedup vs baseline: 1.5121x; 1.2402x over previous
//
#include <hip/hip_runtime.h>

typedef __bf16 bf16;
typedef __bf16 bf16x4 __attribute__((ext_vector_type(4)));
typedef __bf16 bf16x8 __attribute__((ext_vector_type(8)));
typedef float  f32x4  __attribute__((ext_vector_type(4)));

// ---------------------------------------------------------------- helpers
__device__ __forceinline__ void gld16(const void* g, void* l) {
  __builtin_amdgcn_global_load_lds(
      (const __attribute__((address_space(1))) void*)g,
      (__attribute__((address_space(3))) void*)l, 16, 0, 0);
}

// ---------------------------------------------------------------- fused fp32 -> bf16 (all three tensors, one launch)
__global__ void f2bf_all(const float* __restrict__ x, bf16* __restrict__ xo,
                         const float* __restrict__ w1, bf16* __restrict__ w1o,
                         const float* __restrict__ w2, bf16* __restrict__ w2o) {
  int i = blockIdx.x * blockDim.x + threadIdx.x;   // grid covers 2097152 float4s
  const float* in; bf16* out; int idx;
  if (i < 1048576)      { in = x;  out = xo;  idx = i; }
  else if (i < 1835008) { in = w1; out = w1o; idx = i - 1048576; }
  else                  { in = w2; out = w2o; idx = i - 1835008; }
  float4 v = reinterpret_cast<const float4*>(in)[idx];
  bf16x4 o = { (bf16)v.x, (bf16)v.y, (bf16)v.z, (bf16)v.w };
  reinterpret_cast<bf16x4*>(out)[idx] = o;
}

// ---------------------------------------------------------------- GEMM: C[M,N] = A[M,K] * B[N,K]^T + bias
// MODE 0 (BN=128): QKV epilogue. Q/K scatter to [sec][B*H][S][64] (q scaled
//   by 0.125*log2e); V section writes V^T into the V-third of QKV as
//   [B*H][64][2048] (4 consecutive s at fixed d = one bf16x4 store).
// MODE 1 (BN=64): out-proj epilogue -> fp32 C += bias
template<int MODE, int BN>
__global__ __launch_bounds__(256)
void gemm_bt(const bf16* __restrict__ A, const bf16* __restrict__ B,
             const float* __restrict__ bias, void* __restrict__ Cout,
             int K, int N) {
  __shared__ bf16 As[128 * 64];
  __shared__ bf16 Bs[BN * 64];
  const int tid  = threadIdx.x;
  const int wave = tid >> 6, lane = tid & 63;
  const int quad = lane >> 4, l16 = lane & 15;
  const int bm = blockIdx.x * 128, bn = blockIdx.y * BN;
  constexpr int NI  = (BN == 128) ? 4 : 2;
  constexpr int BCH = BN / 32;
  const int wr = (BN == 128) ? (wave >> 1) * 64 : wave * 32;
  const int wc = (BN == 128) ? (wave & 1) * 64 : 0;
  const int arow = lane >> 3;
  const int acol = (lane & 7) * 8;

  f32x4 acc[NI][4] = {};

  const bf16* Ab = A + (size_t)bm * K;
  const bf16* Bb = B + (size_t)bn * K;

  for (int k0 = 0; k0 < K; k0 += 64) {
#pragma unroll
    for (int i = 0; i < 4; ++i) {
      int c = wave * 4 + i;
      gld16(Ab + (size_t)(c * 8 + arow) * K + k0 + acol, As + c * 512);
    }
#pragma unroll
    for (int i = 0; i < BCH; ++i) {
      int c = wave * BCH + i;
      gld16(Bb + (size_t)(c * 8 + arow) * K + k0 + acol, Bs + c * 512);
    }
    __syncthreads();
#pragma unroll
    for (int kk = 0; kk < 64; kk += 32) {
      bf16x8 af[NI], bfr[4];
#pragma unroll
      for (int i = 0; i < NI; ++i)
        af[i]  = *(const bf16x8*)(As + (wr + i * 16 + l16) * 64 + kk + quad * 8);
#pragma unroll
      for (int j = 0; j < 4; ++j)
        bfr[j] = *(const bf16x8*)(Bs + (wc + j * 16 + l16) * 64 + kk + quad * 8);
#pragma unroll
      for (int i = 0; i < NI; ++i)
#pragma unroll
        for (int j = 0; j < 4; ++j)
          acc[i][j] = __builtin_amdgcn_mfma_f32_16x16x32_bf16(af[i], bfr[j], acc[i][j], 0, 0, 0);
    }
    __syncthreads();
  }

  if constexpr (MODE == 0) {
    bf16* Q = (bf16*)Cout;  // [3][32][2048][64]; V-third holds V^T [32][64][2048]
#pragma unroll
    for (int j = 0; j < 4; ++j) {
      int col = bn + wc + j * 16 + l16;
      float bv  = bias[col];
      int sec = col >> 10, rem = col & 1023;
      int h = rem >> 6, d = rem & 63;
      if (sec < 2) {
        float scl = (sec == 0) ? 0.125f * 1.44269504f : 1.0f;
#pragma unroll
        for (int i = 0; i < NI; ++i) {
#pragma unroll
          for (int r = 0; r < 4; ++r) {
            int row = bm + wr + i * 16 + quad * 4 + r;
            int b = row >> 11, si = row & 2047;
            float v = (acc[i][j][r] + bv) * scl;
            Q[(((size_t)sec * 32 + b * 16 + h) * 2048 + si) * 64 + d] = (bf16)v;
          }
        }
      } else {
#pragma unroll
        for (int i = 0; i < NI; ++i) {
          int row0 = bm + wr + i * 16 + quad * 4;
          int b = row0 >> 11, si = row0 & 2047;
          bf16x4 pk = { (bf16)(acc[i][j][0] + bv), (bf16)(acc[i][j][1] + bv),
                        (bf16)(acc[i][j][2] + bv), (bf16)(acc[i][j][3] + bv) };
          *(bf16x4*)(Q + (size_t)2 * 4194304 +
                     ((size_t)(b * 16 + h) * 64 + d) * 2048 + si) = pk;
        }
      }
    }
  } else {
    float* C = (float*)Cout;
#pragma unroll
    for (int j = 0; j < 4; ++j) {
      int col = bn + wc + j * 16 + l16;
      float bv = bias[col];
#pragma unroll
      for (int i = 0; i < NI; ++i)
#pragma unroll
        for (int r = 0; r < 4; ++r) {
          int row = bm + wr + i * 16 + quad * 4 + r;
          C[(size_t)row * N + col] = acc[i][j][r] + bv;
        }
    }
  }
}

// ---------------------------------------------------------------- flash attention v16 = v13 skeleton + in-wave 2-chunk pipeline
// Evidence through v15: v8/v11/v12/v13 all 77-79us at occupancy 18->28%
// (grid fix, LDS cut, reg diet all null); barrier-free K-direct (v15)
// REGRESSED to 129us (L2 redundancy + exposed latency). Diagnosis: the
// invariant is the per-wave IN-ORDER serial chain QK->exp2->pack->PV;
// waves issue in order, so trans and MFMA pipes never overlap within a
// wave, and barriers phase-lock co-resident waves so they contend for
// the same pipe simultaneously (MfmaUtil 17 = 16.6us MFMA; 60% idle).
// v16 tests the last untested mechanism (guide T15, +8-11% attn): make
// the SOURCE ORDER interleave independent phases — QK MFMAs of chunk c+1
// alternate per-nc with exp2/pack of chunk c, so in-order issue overlaps
// MFMA latency with trans work. Tile boundary keeps v13's 2 barriers
// (gld16 staging hidden under the odd-chunk SMPV).
// Dropped: split-KV + combine (v11 direct epilogue; saves a kernel + 33MB
// partial traffic). Kept: 32-qrow/wave x 128-kcol tile, single-buffer Ks
// via gld16 + XOR swizzle (both-sides involution, v13-proven), S^T-form
// QK, per-wave Ps round-trip (in-order DS), V direct from global V^T,
// XCD-local grid (blk%8 = bh%8). Q pre-scaled 0.125*log2e -> exp2.
// Regs ~190 (s x2, bv x2) -> 2 w/SIMD; no cap ((256,2), v10 lesson).
__global__ __launch_bounds__(256, 2)
void attn_kernel(const bf16* __restrict__ QKV, const bf16* __restrict__ Vt,
                 bf16* __restrict__ O) {
  __shared__ bf16 Ks[128 * 64];
  __shared__ bf16 Ps[4][32 * 72];

  const int bh = blockIdx.x;               // XCD-locality: bh is the fast dim
  const int q0 = blockIdx.y * 128;
  const bf16* Qg = QKV + ((size_t)bh * 2048 + q0) * 64;
  const bf16* Kg = QKV + (size_t)32 * 2048 * 64 + (size_t)bh * 2048 * 64;
  const bf16* Vg = Vt + (size_t)bh * 64 * 2048;

  const int tid  = threadIdx.x;
  const int wave = tid >> 6, lane = tid & 63;
  const int quad = lane >> 4, l16 = lane & 15;
  const int srow = tid >> 3;            // 0..31 staging row
  const int swcol = ((tid & 7) * 8) ^ ((srow & 7) << 3);  // pre-swizzled src col
  const int xrd = (l16 & 7) << 3;       // read-side XOR (row&7 == l16&7)
  bf16* Pw = &Ps[wave][0];

  // Q fragments in registers (B-operand), reused across all 16 K-tiles
  bf16x8 aq[2][2];
#pragma unroll
  for (int i = 0; i < 2; ++i)
#pragma unroll
    for (int kh = 0; kh < 2; ++kh)
      aq[i][kh] = *(const bf16x8*)(Qg + (size_t)(wave * 32 + i * 16 + l16) * 64 +
                                   kh * 32 + quad * 8);

  float rs[2] = {0.f, 0.f};             // per-lane partial row sums (qrow = i*16+l16)
  f32x4 o[2][4] = {};

  // ---- macros-as-lambdas ------------------------------------------------
  auto QK = [&](f32x4 s[2][4], int g, int c) {
#pragma unroll
    for (int kh = 0; kh < 2; ++kh)
#pragma unroll
      for (int nc = 0; nc < 4; ++nc) {
        int row = (c * 4 + nc) * 16 + l16;
        bf16x8 bk = *(const bf16x8*)(&Ks[row * 64 + ((kh * 32 + quad * 8) ^ xrd)]);
        s[0][nc] = __builtin_amdgcn_mfma_f32_16x16x32_bf16(bk, aq[0][kh], s[0][nc], 0, 0, 0);
        s[1][nc] = __builtin_amdgcn_mfma_f32_16x16x32_bf16(bk, aq[1][kh], s[1][nc], 0, 0, 0);
      }
  };
  auto LDV = [&](bf16x8 bv[2][4], int g, int c) {
#pragma unroll
    for (int kc = 0; kc < 2; ++kc)
#pragma unroll
      for (int oj = 0; oj < 4; ++oj)
        bv[kc][oj] = *(const bf16x8*)(Vg + (size_t)(oj * 16 + l16) * 2048 +
                                      g * 128 + (c * 2 + kc) * 32 + quad * 8);
  };
  auto SMcol = [&](f32x4 s[2][4], int nc) {
#pragma unroll
    for (int i = 0; i < 2; ++i) {
      float p0 = __builtin_amdgcn_exp2f(s[i][nc][0]);
      float p1 = __builtin_amdgcn_exp2f(s[i][nc][1]);
      float p2 = __builtin_amdgcn_exp2f(s[i][nc][2]);
      float p3 = __builtin_amdgcn_exp2f(s[i][nc][3]);
      rs[i] += (p0 + p1) + (p2 + p3);
      bf16x4 pk = { (bf16)p0, (bf16)p1, (bf16)p2, (bf16)p3 };
      *(bf16x4*)(Pw + (i * 16 + l16) * 72 + nc * 16 + quad * 4) = pk;
    }
  };
  auto PV = [&](bf16x8 bv[2][4]) {
#pragma unroll
    for (int kc = 0; kc < 2; ++kc)
#pragma unroll
      for (int i = 0; i < 2; ++i) {
        bf16x8 ap = *(const bf16x8*)(Pw + (i * 16 + l16) * 72 + kc * 32 + quad * 8);
#pragma unroll
        for (int oj = 0; oj < 4; ++oj)
          o[i][oj] = __builtin_amdgcn_mfma_f32_16x16x32_bf16(ap, bv[kc][oj], o[i][oj], 0, 0, 0);
      }
  };

  // ---- prologue: stage tile 0, first QK ---------------------------------
#pragma unroll
  for (int ch = 0; ch < 4; ++ch)
    gld16(Kg + (size_t)(0 * 128 + ch * 32 + srow) * 64 + swcol,
          Ks + ch * 2048 + wave * 512);
  __syncthreads();

  bf16x8 bv0[2][4], bv1[2][4];
  f32x4 s_cur[2][4] = {}, s_nxt[2][4];
  LDV(bv0, 0, 0);
  QK(s_cur, 0, 0);

  for (int t = 0; t < 16; ++t) {
    // (a) pipelined pair: QK(chunk1) interleaved per-nc with SM(chunk0)
    LDV(bv1, t, 1);
#pragma unroll
    for (int nc = 0; nc < 4; ++nc) s_nxt[0][nc] = f32x4{}, s_nxt[1][nc] = f32x4{};
#pragma unroll
    for (int nc = 0; nc < 4; ++nc) {
      // QK next chunk, column nc (4 MFMAs)
#pragma unroll
      for (int kh = 0; kh < 2; ++kh) {
        int row = (4 + nc) * 16 + l16;
        bf16x8 bk = *(const bf16x8*)(&Ks[row * 64 + ((kh * 32 + quad * 8) ^ xrd)]);
        s_nxt[0][nc] = __builtin_amdgcn_mfma_f32_16x16x32_bf16(bk, aq[0][kh], s_nxt[0][nc], 0, 0, 0);
        s_nxt[1][nc] = __builtin_amdgcn_mfma_f32_16x16x32_bf16(bk, aq[1][kh], s_nxt[1][nc], 0, 0, 0);
      }
      // SM current chunk, column nc (8 exp2 on the trans pipe)
      SMcol(s_cur, nc);
    }
    PV(bv0);                            // chunk0 PV

    // (b) tile boundary: all Ks reads of tile t done
    __syncthreads();
    if (t < 15) {
#pragma unroll
      for (int ch = 0; ch < 4; ++ch)
        gld16(Kg + (size_t)((t + 1) * 128 + ch * 32 + srow) * 64 + swcol,
              Ks + ch * 2048 + wave * 512);
    }
    // SMPV(chunk1) hides the staging latency
#pragma unroll
    for (int nc = 0; nc < 4; ++nc) SMcol(s_nxt, nc);
    PV(bv1);
    if (t < 15) {
      __syncthreads();                  // vmcnt drained; new Ks visible
      LDV(bv0, t + 1, 0);
#pragma unroll
      for (int nc = 0; nc < 4; ++nc) s_cur[0][nc] = f32x4{}, s_cur[1][nc] = f32x4{};
      QK(s_cur, t + 1, 0);
    }
  }

  // ---- finalize row sums: quads hold partials for row l16
#pragma unroll
  for (int i = 0; i < 2; ++i) {
    rs[i] += __shfl_xor(rs[i], 16);
    rs[i] += __shfl_xor(rs[i], 32);
  }

  // ---- epilogue: redistribute 1/l to C-layout rows, write bf16
  const int b = bh >> 4, h = bh & 15;
#pragma unroll
  for (int i = 0; i < 2; ++i)
#pragma unroll
    for (int r = 0; r < 4; ++r) {
      float lsum = __shfl(rs[i], quad * 4 + r);   // sum for row quad*4+r (at lane l16=row)
      float inv = 1.0f / lsum;
      int row = q0 + wave * 32 + i * 16 + quad * 4 + r;
#pragma unroll
      for (int oj = 0; oj < 4; ++oj)
        O[((size_t)(b * 2048 + row)) * 1024 + h * 64 + oj * 16 + l16] =
            (bf16)(o[i][oj][r] * inv);
    }
}

// ---------------------------------------------------------------- launch
extern "C" void kernel_launch(void* const* d_in, const int* in_sizes, int n_in,
                              void* d_out, int out_size, void* d_ws, size_t ws_size,
                              hipStream_t stream) {
  const float* x      = (const float*)d_in[0];   // [2,2048,1024]
  const float* qkv_w  = (const float*)d_in[1];   // [3072,1024]
  const float* qkv_b  = (const float*)d_in[2];   // [3072]
  const float* out_w  = (const float*)d_in[3];   // [1024,1024]
  const float* out_b  = (const float*)d_in[4];   // [1024]
  float* out = (float*)d_out;                    // [2,2048,1024] fp32

  char* ws = (char*)d_ws;
  bf16* Xb   = (bf16*)(ws);                      // 8 MB
  bf16* Wqkv = (bf16*)(ws + 8388608);            // 6 MB
  bf16* Wout = (bf16*)(ws + 14680064);           // 2 MB
  bf16* QKV  = (bf16*)(ws + 16777216);           // 24 MB: [Q][K] + V^T third
  bf16* At   = (bf16*)(ws + 41943040);           // 8 MB attn output [B,S,1024]
  bf16* VtP  = QKV + (size_t)2 * 32 * 2048 * 64; // V^T [32][64][2048]

  f2bf_all<<<8192, 256, 0, stream>>>(x, Xb, qkv_w, Wqkv, out_w, Wout);

  gemm_bt<0, 128><<<dim3(32, 24), 256, 0, stream>>>(Xb, Wqkv, qkv_b, (void*)QKV, 1024, 3072);

  // grid (bh, q_tile): blk%8 = bh%8 -> per-head XCD locality (K/V in one L2)
  attn_kernel<<<dim3(32, 16), 256, 0, stream>>>(QKV, VtP, At);

  gemm_bt<1, 64><<<dim3(32, 16), 256, 0, stream>>>(At, Wout, out_b, (void*)out, 1024, 1024);
}